// Round 4
// baseline (196.814 us; speedup 1.0000x reference)
//
#include <hip/hip_runtime.h>

#define NUM_CODES 1024
#define CODE_DIM  256
#define N_ROWS    32768

// output layout (floats)
#define ZQ_OFF    0
#define LOSS_OFF  8388608
#define IDX_OFF   8388609
#define CS_OFF    8421377
#define NEA_OFF   8422401
#define NORM_OFF  8684545

#define EMA       0.99f
#define ONE_M_EMA 0.01f
#define EPSF      1e-6f
#define LOSS_SCALE (0.25f / 8388608.0f)

// ws layout (bytes)
#define WS_N_B      0                     // float n
#define WS_ENORM_B  64                    // 1024 floats
#define WS_CNT_B    (WS_ENORM_B + 4096)   // 1024 uint counts
#define WS_OFF_B    (WS_CNT_B + 4096)     // 1024 uint exclusive offsets
#define WS_CUR_B    (WS_OFF_B + 4096)     // 1024 uint cursors
#define WS_IDX_B    (WS_CUR_B + 4096)     // 32768 uint per-row code
#define WS_LIST_B   (WS_IDX_B + 131072)   // 32768 uint row list
#define WS_EH_B     (WS_LIST_B + 131072)  // 512 KB E hi frag-major
#define WS_EL_B     (WS_EH_B + 524288)    // 512 KB E lo

typedef __attribute__((ext_vector_type(8))) short short8;
typedef __attribute__((ext_vector_type(4))) float f32x4;

__device__ __forceinline__ unsigned short f2bf(float x) {
  union { float f; unsigned u; } v; v.f = x;
  unsigned r = v.u + 0x7fffu + ((v.u >> 16) & 1u);
  return (unsigned short)(r >> 16);
}
__device__ __forceinline__ float bf2f(unsigned short b) {
  union { unsigned u; float f; } v; v.u = ((unsigned)b) << 16;
  return v.f;
}

typedef const __attribute__((address_space(1))) unsigned char* gas_t;
typedef __attribute__((address_space(3))) unsigned char* las_t;
__device__ __forceinline__ void gl_lds16(const void* g, void* l) {
  __builtin_amdgcn_global_load_lds((gas_t)g, (las_t)l, 16, 0, 0);
}

// ---------------------------------------------------------------- K0: setup
// E split hi/lo frag-major [plane][code][8]; enorm; zero loss + counts
__global__ void k_setup(const float* __restrict__ emb, float* __restrict__ out,
                        float* __restrict__ wsf) {
  const int b = blockIdx.x, t = threadIdx.x;
  char* wsb = (char*)wsf;
  if (b < 4) {
    ((unsigned*)(wsb + WS_CNT_B))[b * 256 + t] = 0u;
    if (b == 0 && t == 0) out[LOSS_OFF] = 0.0f;
  }
  float x = emb[(long)b * CODE_DIM + t];
  unsigned short hb = f2bf(x);
  unsigned short lb = f2bf(x - bf2f(hb));
  unsigned short* eh = (unsigned short*)(wsb + WS_EH_B);
  unsigned short* el = (unsigned short*)(wsb + WS_EL_B);
  int p = t >> 3, j = t & 7;                 // plane = k/8, elem = k%8
  long eo = ((long)p * NUM_CODES + b) * 8 + j;
  eh[eo] = hb; el[eo] = lb;
  float v = x * x;
  #pragma unroll
  for (int o = 32; o >= 1; o >>= 1) v += __shfl_xor(v, o);
  __shared__ float s[4];
  if ((t & 63) == 0) s[t >> 6] = v;
  __syncthreads();
  if (t == 0) ((float*)(wsb + WS_ENORM_B))[b] = s[0] + s[1] + s[2] + s[3];
}

// ---------------------------------------------------------------- K1: main GEMM+argmin
#define BM        64         // rows per block = 2 waves x 32 rows
#define NC        32         // codes per chunk
#define NCHUNK    32
#define CHUNK_B   32768      // hi(16KB) + lo(16KB)

__launch_bounds__(128, 1)
__global__ void k_main(const float* __restrict__ z, const float* __restrict__ wsf,
                       float* __restrict__ out) {
  __shared__ __align__(16) unsigned char lds[2 * CHUNK_B];
  __shared__ int s_idx[BM];

  const char* wsb = (const char*)wsf;
  const float* enp = (const float*)(wsb + WS_ENORM_B);
  const int tid = threadIdx.x;
  const int w   = tid >> 6;      // wave 0..1
  const int l   = tid & 63;
  const int mrow = l & 15;
  const int kq   = l >> 4;
  const int row0 = blockIdx.x * BM;

  // ---- A: 32 rows per wave (2 mtiles), hi/lo bf16 fragments in registers
  short8 aH0[8], aL0[8], aH1[8], aL1[8];
  {
    const float* zr0 = z + (long)(row0 + w * 32 + mrow) * CODE_DIM + kq * 8;
    const float* zr1 = zr0 + 16 * CODE_DIM;
    #pragma unroll
    for (int ks = 0; ks < 8; ++ks) {
      float4 f0 = *(const float4*)(zr0 + ks * 32);
      float4 f1 = *(const float4*)(zr0 + ks * 32 + 4);
      float4 g0 = *(const float4*)(zr1 + ks * 32);
      float4 g1 = *(const float4*)(zr1 + ks * 32 + 4);
      float xs[8] = {f0.x, f0.y, f0.z, f0.w, f1.x, f1.y, f1.z, f1.w};
      float ys[8] = {g0.x, g0.y, g0.z, g0.w, g1.x, g1.y, g1.z, g1.w};
      #pragma unroll
      for (int j = 0; j < 8; ++j) {
        unsigned short hb = f2bf(xs[j]);
        aH0[ks][j] = (short)hb; aL0[ks][j] = (short)f2bf(xs[j] - bf2f(hb));
        unsigned short hc = f2bf(ys[j]);
        aH1[ks][j] = (short)hc; aL1[ks][j] = (short)f2bf(ys[j] - bf2f(hc));
      }
    }
  }

  auto stage = [&](int chunk, int buf) {
    #pragma unroll
    for (int it = 0; it < 16; ++it) {
      int d  = (it * 128 + tid) * 16;      // 0..32752
      int s  = d >> 14;                    // 0 = hi, 1 = lo
      int d2 = d & 16383;
      int p  = d2 >> 9;                    // plane 0..31
      int in_ = d2 & 511;                  // 32 codes * 16B
      const char* src = wsb + (s ? WS_EL_B : WS_EH_B) + p * 16384 + chunk * 512 + in_;
      gl_lds16(src, (void*)(lds + buf * CHUNK_B + d));
    }
  };

  float best0[4], best1[4]; int bidx0[4], bidx1[4];
  #pragma unroll
  for (int r = 0; r < 4; ++r) {
    best0[r] = 3.0e38f; bidx0[r] = 0; best1[r] = 3.0e38f; bidx1[r] = 0;
  }

  stage(0, 0);
  for (int c = 0; c < NCHUNK; ++c) {
    __syncthreads();
    if (c + 1 < NCHUNK) stage(c + 1, (c + 1) & 1);
    const unsigned char* base = lds + (c & 1) * CHUNK_B;
    #pragma unroll
    for (int nt = 0; nt < 2; ++nt) {
      f32x4 aA0 = {0,0,0,0}, aB0 = {0,0,0,0}, aC0 = {0,0,0,0};
      f32x4 aA1 = {0,0,0,0}, aB1 = {0,0,0,0}, aC1 = {0,0,0,0};
      const int ci = nt * 16 + mrow;
      #pragma unroll
      for (int ks = 0; ks < 8; ++ks) {
        const int p = ks * 4 + kq;
        short8 bh = *(const short8*)(base + (p * NC + ci) * 16);
        short8 bl = *(const short8*)(base + 16384 + (p * NC + ci) * 16);
        aA0 = __builtin_amdgcn_mfma_f32_16x16x32_bf16(aH0[ks], bh, aA0, 0, 0, 0);
        aA1 = __builtin_amdgcn_mfma_f32_16x16x32_bf16(aH1[ks], bh, aA1, 0, 0, 0);
        aB0 = __builtin_amdgcn_mfma_f32_16x16x32_bf16(aL0[ks], bh, aB0, 0, 0, 0);
        aB1 = __builtin_amdgcn_mfma_f32_16x16x32_bf16(aL1[ks], bh, aB1, 0, 0, 0);
        aC0 = __builtin_amdgcn_mfma_f32_16x16x32_bf16(aH0[ks], bl, aC0, 0, 0, 0);
        aC1 = __builtin_amdgcn_mfma_f32_16x16x32_bf16(aH1[ks], bl, aC1, 0, 0, 0);
      }
      const int code = c * NC + nt * 16 + mrow;
      const float en = enp[code];
      #pragma unroll
      for (int r = 0; r < 4; ++r) {
        float d0 = aA0[r] + aB0[r] + aC0[r];
        float s0 = fmaf(-2.0f, d0, en);
        if (s0 < best0[r]) { best0[r] = s0; bidx0[r] = code; }
        float d1 = aA1[r] + aB1[r] + aC1[r];
        float s1 = fmaf(-2.0f, d1, en);
        if (s1 < best1[r]) { best1[r] = s1; bidx1[r] = code; }
      }
    }
  }

  // cross-lane argmin over the 16-lane code field, lowest-idx tie-break
  #pragma unroll
  for (int r = 0; r < 4; ++r) {
    float v = best0[r]; int ix = bidx0[r];
    #pragma unroll
    for (int o = 1; o < 16; o <<= 1) {
      float v2 = __shfl_xor(v, o); int x2 = __shfl_xor(ix, o);
      if (v2 < v || (v2 == v && x2 < ix)) { v = v2; ix = x2; }
    }
    if (mrow == 0) s_idx[w * 32 + kq * 4 + r] = ix;
    float u = best1[r]; int iy = bidx1[r];
    #pragma unroll
    for (int o = 1; o < 16; o <<= 1) {
      float u2 = __shfl_xor(u, o); int y2 = __shfl_xor(iy, o);
      if (u2 < u || (u2 == u && y2 < iy)) { u = u2; iy = y2; }
    }
    if (mrow == 0) s_idx[w * 32 + 16 + kq * 4 + r] = iy;
  }
  __syncthreads();

  if (tid < BM) {
    int ix = s_idx[tid];
    out[IDX_OFF + row0 + tid] = (float)ix;
    ((unsigned*)((char*)wsf + WS_IDX_B))[row0 + tid] = (unsigned)ix;
    atomicAdd(&((unsigned*)((char*)wsf + WS_CNT_B))[ix], 1u);
  }
}

// ---------------------------------------------------------------- K2: scan (1 block)
__global__ void k_scan(const float* __restrict__ cs_in, float* __restrict__ out,
                       float* __restrict__ wsf) {
  __shared__ unsigned ps[NUM_CODES];
  __shared__ float ns[16];
  char* wsb = (char*)wsf;
  const int t = threadIdx.x;  // 1024
  unsigned cnt = ((unsigned*)(wsb + WS_CNT_B))[t];
  float ncs = EMA * cs_in[t] + ONE_M_EMA * (float)cnt;
  out[CS_OFF + t] = ncs;
  // n = sum(ncs)
  float v = ncs;
  #pragma unroll
  for (int o = 32; o >= 1; o >>= 1) v += __shfl_xor(v, o);
  if ((t & 63) == 0) ns[t >> 6] = v;
  // prefix sum of counts (Hillis-Steele, inclusive)
  ps[t] = cnt;
  __syncthreads();
  #pragma unroll
  for (int o = 1; o < NUM_CODES; o <<= 1) {
    unsigned add = (t >= o) ? ps[t - o] : 0u;
    __syncthreads();
    ps[t] += add;
    __syncthreads();
  }
  unsigned excl = ps[t] - cnt;
  ((unsigned*)(wsb + WS_OFF_B))[t] = excl;
  ((unsigned*)(wsb + WS_CUR_B))[t] = excl;
  if (t == 0) {
    float n = 0.0f;
    #pragma unroll
    for (int k = 0; k < 16; ++k) n += ns[k];
    *((float*)(wsb + WS_N_B)) = n;
  }
}

// ---------------------------------------------------------------- K3: scatter row ids
__global__ void k_scatter(float* __restrict__ wsf) {
  char* wsb = (char*)wsf;
  int r = blockIdx.x * 256 + threadIdx.x;
  unsigned ix = ((unsigned*)(wsb + WS_IDX_B))[r];
  unsigned slot = atomicAdd(&((unsigned*)(wsb + WS_CUR_B))[ix], 1u);
  ((unsigned*)(wsb + WS_LIST_B))[slot] = r;
}

// ---------------------------------------------------------------- K4: per-code gather
// z_q, loss, embed_sum, nea, norm — no nea atomics, all coalesced
__global__ void k_gather(const float* __restrict__ z, const float* __restrict__ emb,
                         const float* __restrict__ ea, float* __restrict__ out,
                         const float* __restrict__ wsf) {
  __shared__ unsigned slist[4096];
  __shared__ float sl[4];
  const char* wsb = (const char*)wsf;
  const int k = blockIdx.x, t = threadIdx.x;
  const unsigned cnt = ((const unsigned*)(wsb + WS_CNT_B))[k];
  const unsigned off = ((const unsigned*)(wsb + WS_OFF_B))[k];
  const unsigned* list = (const unsigned*)(wsb + WS_LIST_B);

  const float e = emb[(long)k * CODE_DIM + t];
  float sum = 0.0f, lacc = 0.0f;

  for (unsigned base = 0; base < cnt; base += 4096) {
    unsigned m = cnt - base; if (m > 4096) m = 4096;
    for (unsigned i = t; i < m; i += 256) slist[i] = list[off + base + i];
    __syncthreads();
    for (unsigned i = 0; i < m; ++i) {
      long zo = (long)slist[i] * CODE_DIM + t;
      float x = z[zo];
      float d = e - x;
      out[ZQ_OFF + zo] = x + d;        // straight-through, matches ref rounding
      lacc += d * d;
      sum += x;
    }
    __syncthreads();
  }

  long o = (long)k * CODE_DIM + t;
  float nea = EMA * ea[o] + ONE_M_EMA * sum;
  out[NEA_OFF + o] = nea;
  float n   = *((const float*)(wsb + WS_N_B));
  float ncs = out[CS_OFF + k];
  float cs  = (ncs + EPSF) / (n + (float)NUM_CODES * EPSF) * n;
  cs = fmaxf(cs, EPSF);
  out[NORM_OFF + o] = nea / cs;

  #pragma unroll
  for (int ofs = 32; ofs >= 1; ofs >>= 1) lacc += __shfl_xor(lacc, ofs);
  if ((t & 63) == 0) sl[t >> 6] = lacc;
  __syncthreads();
  if (t == 0)
    atomicAdd(&out[LOSS_OFF], (sl[0] + sl[1] + sl[2] + sl[3]) * LOSS_SCALE);
}

// ---------------------------------------------------------------- launch
extern "C" void kernel_launch(void* const* d_in, const int* in_sizes, int n_in,
                              void* d_out, int out_size, void* d_ws, size_t ws_size,
                              hipStream_t stream) {
  const float* z   = (const float*)d_in[0];
  const float* emb = (const float*)d_in[1];
  const float* cs  = (const float*)d_in[2];
  const float* ea  = (const float*)d_in[3];
  float* out = (float*)d_out;
  float* wsf = (float*)d_ws;

  hipLaunchKernelGGL(k_setup,   dim3(NUM_CODES), dim3(256), 0, stream, emb, out, wsf);
  hipLaunchKernelGGL(k_main,    dim3(N_ROWS / BM), dim3(128), 0, stream, z, wsf, out);
  hipLaunchKernelGGL(k_scan,    dim3(1), dim3(1024), 0, stream, cs, out, wsf);
  hipLaunchKernelGGL(k_scatter, dim3(N_ROWS / 256), dim3(256), 0, stream, wsf);
  hipLaunchKernelGGL(k_gather,  dim3(NUM_CODES), dim3(256), 0, stream, z, emb, ea, out, wsf);
}